// Round 1
// baseline (637.305 us; speedup 1.0000x reference)
//
#include <hip/hip_runtime.h>

#define F_N   150000
#define K_N   5
#define S_N   32
#define V_N   100000
#define NITER 5
#define MLP_N 330
#define SHIFTV (-500.0f)

__device__ __forceinline__ float lse2(float a, float b) {
    float mx = fmaxf(a, b);
    return mx + __logf(__expf(a - mx) + __expf(b - mx));
}

// ---------------- K0: m_1 from (prv_fb, prv_v2f); scatter vbacc_1; count deg ----
__global__ __launch_bounds__(256) void k_init(
    const float* __restrict__ prv_fb,   // [F][32]
    const float* __restrict__ prv_v2f,  // [F][5][2]
    const int*   __restrict__ vidx,     // [F][5]
    float*       __restrict__ m_out,    // SoA [10][F]
    float*       __restrict__ vbacc,    // [V][2]
    float*       __restrict__ deg)      // [V]
{
    int f = blockIdx.x * 256 + threadIdx.x;
    if (f >= F_N) return;

    float fb[S_N];
    const float4* p4 = reinterpret_cast<const float4*>(prv_fb + (size_t)f * S_N);
    #pragma unroll
    for (int i = 0; i < S_N / 4; ++i) {
        float4 v = p4[i];
        fb[i*4+0] = v.x; fb[i*4+1] = v.y; fb[i*4+2] = v.z; fb[i*4+3] = v.w;
    }
    float M = fb[0];
    #pragma unroll
    for (int s = 1; s < S_N; ++s) M = fmaxf(M, fb[s]);
    float T = 0.0f;
    float S0[K_N] = {0.f, 0.f, 0.f, 0.f, 0.f};
    #pragma unroll
    for (int s = 0; s < S_N; ++s) {
        float t = __expf(fb[s] - M);
        T += t;
        #pragma unroll
        for (int k = 0; k < K_N; ++k)
            if (((s >> k) & 1) == 0) S0[k] += t;
    }
    #pragma unroll
    for (int k = 0; k < K_N; ++k) {
        float v0 = prv_v2f[(size_t)f * (K_N*2) + k*2 + 0];
        float v1 = prv_v2f[(size_t)f * (K_N*2) + k*2 + 1];
        float u0 = __logf(S0[k])     - v0;
        float u1 = __logf(T - S0[k]) - v1;
        float l  = lse2(u0, u1);
        float m0 = u0 - l, m1 = u1 - l;
        m_out[(k*2+0)*F_N + f] = m0;
        m_out[(k*2+1)*F_N + f] = m1;
        int v = vidx[(size_t)f * K_N + k];
        atomicAdd(&vbacc[v*2+0], m0);
        atomicAdd(&vbacc[v*2+1], m1);
        atomicAdd(&deg[v], 1.0f);
    }
}

// ---------------- fused iteration kernel ---------------------------------------
// factor blocks: v2f_i, fb_i (registers only), features_i, m_{i+1}, scatter vbacc_{i+1}
// extra blocks:  var_term_i from vbacc_i (normalized) and deg
template <bool LAST>
__global__ __launch_bounds__(256) void k_iter(
    const float* __restrict__ pot,      // [F][32]
    const int*   __restrict__ vidx,     // [F][5]
    const float* __restrict__ m_in,     // SoA [10][F]
    float*       __restrict__ m_out,    // SoA [10][F] (unused if LAST)
    const float* __restrict__ vb_in,    // [V][2] accumulated (unnormalized)
    float*       __restrict__ vb_out,   // [V][2] (unused if LAST)
    const float* __restrict__ deg,      // [V]
    float*       __restrict__ x,        // [330] pooled features (atomic accum)
    int iter)                           // 0-based
{
    const int FBLK = (F_N + 255) / 256;
    const int lane = threadIdx.x & 63;
    __shared__ float red[256];

    if ((int)blockIdx.x >= FBLK) {
        // ---- var_term for this iteration ----
        int v = ((int)blockIdx.x - FBLK) * 256 + threadIdx.x;
        float c0 = 0.0f, c1 = 0.0f;
        if (v < V_N) {
            float a0 = vb_in[v*2+0], a1 = vb_in[v*2+1];
            float l = lse2(a0, a1);
            float vb0 = a0 - l, vb1 = a1 - l;
            float dm1 = deg[v] - 1.0f;
            c0 = dm1 * __expf(vb0) * vb0;
            c1 = dm1 * __expf(vb1) * vb1;
        }
        #pragma unroll
        for (int mk = 32; mk >= 1; mk >>= 1) {
            c0 += __shfl_xor(c0, mk);
            c1 += __shfl_xor(c1, mk);
        }
        if (lane == 0) {
            atomicAdd(&x[iter*66 + 64], c0);
            atomicAdd(&x[iter*66 + 65], c1);
        }
        return;
    }

    // ---- factor path ----
    int f = blockIdx.x * 256 + threadIdx.x;
    bool valid = f < F_N;
    int fc = valid ? f : (F_N - 1);

    float m[K_N][2];
    #pragma unroll
    for (int k = 0; k < K_N; ++k) {
        m[k][0] = m_in[(k*2+0)*F_N + fc];
        m[k][1] = m_in[(k*2+1)*F_N + fc];
    }
    int vi[K_N];
    #pragma unroll
    for (int k = 0; k < K_N; ++k) vi[k] = vidx[(size_t)fc * K_N + k];

    float v2f[K_N][2];
    #pragma unroll
    for (int k = 0; k < K_N; ++k) {
        float a0 = vb_in[vi[k]*2+0] - m[k][0];
        float a1 = vb_in[vi[k]*2+1] - m[k][1];
        float l = lse2(a0, a1);
        v2f[k][0] = a0 - l;
        v2f[k][1] = a1 - l;
    }

    float potr[S_N];
    const float4* p4 = reinterpret_cast<const float4*>(pot + (size_t)fc * S_N);
    #pragma unroll
    for (int i = 0; i < S_N / 4; ++i) {
        float4 v = p4[i];
        potr[i*4+0] = v.x; potr[i*4+1] = v.y; potr[i*4+2] = v.z; potr[i*4+3] = v.w;
    }

    float fb[S_N];
    #pragma unroll
    for (int s = 0; s < S_N; ++s) {
        float w = v2f[0][s & 1] + v2f[1][(s >> 1) & 1] + v2f[2][(s >> 2) & 1]
                + v2f[3][(s >> 3) & 1] + v2f[4][(s >> 4) & 1];
        fb[s] = potr[s] + w;
    }
    float M = fb[0];
    #pragma unroll
    for (int s = 1; s < S_N; ++s) M = fmaxf(M, fb[s]);

    float T = 0.0f;
    float S0[K_N] = {0.f, 0.f, 0.f, 0.f, 0.f};
    #pragma unroll
    for (int s = 0; s < S_N; ++s) {
        float t = __expf(fb[s] - M);
        T += t;
        #pragma unroll
        for (int k = 0; k < K_N; ++k)
            if (((s >> k) & 1) == 0) S0[k] += t;
    }

    if (!LAST) {
        #pragma unroll
        for (int k = 0; k < K_N; ++k) {
            float u0 = __logf(S0[k])     - v2f[k][0];
            float u1 = __logf(T - S0[k]) - v2f[k][1];
            float l  = lse2(u0, u1);
            float m0 = u0 - l, m1 = u1 - l;
            if (valid) {
                m_out[(k*2+0)*F_N + f] = m0;
                m_out[(k*2+1)*F_N + f] = m1;
                atomicAdd(&vb_out[vi[k]*2+0], m0);
                atomicAdd(&vb_out[vi[k]*2+1], m1);
            }
        }
    }

    // ---- pooled features: energy[32] | fac_ent[32] ----
    float invT = 1.0f / T;
    float logT = __logf(T);
    float arr[2 * S_N];
    #pragma unroll
    for (int s = 0; s < S_N; ++s) {
        float p   = __expf(fb[s] - M) * invT;   // exp(fb_norm)
        float fbn = fb[s] - M - logT;           // normalized fb
        arr[s]       = valid ? p * potr[s] : 0.0f;
        arr[S_N + s] = valid ? -p * fbn    : 0.0f;
    }

    // recursive-halving reduce: 64 values over 64 lanes -> lane L holds sum of value L
    #pragma unroll
    for (int mk = 32; mk >= 1; mk >>= 1) {
        bool upper = (lane & mk) != 0;
        #pragma unroll
        for (int j = 0; j < mk; ++j) {
            float send = upper ? arr[j] : arr[j + mk];
            float recv = __shfl_xor(send, mk);
            float keep = upper ? arr[j + mk] : arr[j];
            arr[j] = keep + recv;
        }
    }

    // cross-wave combine in LDS, then one atomic per feature per block
    red[threadIdx.x] = arr[0];
    __syncthreads();
    if (threadIdx.x < 64) {
        float s = red[threadIdx.x] + red[64 + threadIdx.x]
                + red[128 + threadIdx.x] + red[192 + threadIdx.x];
        atomicAdd(&x[iter*66 + threadIdx.x], s);
    }
}

// ---------------- MLP ----------------------------------------------------------
__global__ __launch_bounds__(64) void k_mlp1(
    const float* __restrict__ x, const float* __restrict__ w1,
    const float* __restrict__ b1, float* __restrict__ h)
{
    int j = blockIdx.x;
    int lane = threadIdx.x;
    float s = 0.0f;
    for (int i = lane; i < MLP_N; i += 64) s += x[i] * w1[(size_t)j * MLP_N + i];
    #pragma unroll
    for (int mk = 32; mk >= 1; mk >>= 1) s += __shfl_xor(s, mk);
    if (lane == 0) h[j] = fmaxf(s + b1[j], SHIFTV);
}

__global__ __launch_bounds__(64) void k_mlp2(
    const float* __restrict__ h, const float* __restrict__ w2,
    const float* __restrict__ b2, float* __restrict__ out)
{
    int lane = threadIdx.x;
    float s = 0.0f;
    for (int i = lane; i < MLP_N; i += 64) s += h[i] * w2[i];
    #pragma unroll
    for (int mk = 32; mk >= 1; mk >>= 1) s += __shfl_xor(s, mk);
    if (lane == 0) out[0] = fmaxf(s + b2[0], SHIFTV);
}

// ---------------- launch --------------------------------------------------------
extern "C" void kernel_launch(void* const* d_in, const int* in_sizes, int n_in,
                              void* d_out, int out_size, void* d_ws, size_t ws_size,
                              hipStream_t stream)
{
    (void)in_sizes; (void)n_in; (void)out_size; (void)ws_size;
    const float* pot  = (const float*)d_in[0];
    const int*   vidx = (const int*)  d_in[1];
    const float* pv2f = (const float*)d_in[2];
    // d_in[3] = prv_f2v (unused by the reference)
    const float* pfb  = (const float*)d_in[4];
    const float* w1   = (const float*)d_in[5];
    const float* b1   = (const float*)d_in[6];
    const float* w2   = (const float*)d_in[7];
    const float* b2   = (const float*)d_in[8];

    float* ws  = (float*)d_ws;
    float* m_a = ws;                       // 10*F
    float* m_b = m_a + 10 * F_N;           // 10*F
    float* vb  = m_b + 10 * F_N;           // 5 * V * 2 (one buffer per iteration)
    float* deg = vb + 5 * 2 * V_N;         // V
    float* x   = deg + V_N;                // 330
    float* h   = x + MLP_N;                // 330

    // zero vbacc buffers + deg + x (contiguous)
    size_t zbytes = (size_t)(5 * 2 * V_N + V_N + MLP_N) * sizeof(float);
    hipMemsetAsync(vb, 0, zbytes, stream);

    const int FBLK = (F_N + 255) / 256;
    const int VBLK = (V_N + 255) / 256;

    k_init<<<FBLK, 256, 0, stream>>>(pfb, pv2f, vidx, m_a, vb, deg);

    float* mi = m_a;
    float* mo = m_b;
    for (int it = 0; it < NITER; ++it) {
        float* vbi = vb + (size_t)it * 2 * V_N;
        if (it < NITER - 1) {
            float* vbo = vb + (size_t)(it + 1) * 2 * V_N;
            k_iter<false><<<FBLK + VBLK, 256, 0, stream>>>(
                pot, vidx, mi, mo, vbi, vbo, deg, x, it);
        } else {
            k_iter<true><<<FBLK + VBLK, 256, 0, stream>>>(
                pot, vidx, mi, nullptr, vbi, nullptr, deg, x, it);
        }
        float* t = mi; mi = mo; mo = t;
    }

    k_mlp1<<<MLP_N, 64, 0, stream>>>(x, w1, b1, h);
    k_mlp2<<<1, 64, 0, stream>>>(h, w2, b2, (float*)d_out);
}

// Round 2
// 484.042 us; speedup vs baseline: 1.3166x; 1.3166x over previous
//
#include <hip/hip_runtime.h>

#define F_N   150000
#define K_N   5
#define S_N   32
#define V_N   100000
#define NITER 5
#define MLP_N 330
#define SHIFTV (-500.0f)

#define FBLK  ((F_N + 255) / 256)     // 587
#define VBLK  ((V_N + 255) / 256)     // 391
#define EBLK  ((F_N * K_N + 255) / 256) // 2930

__device__ __forceinline__ float lse2(float a, float b) {
    float mx = fmaxf(a, b);
    return mx + __logf(__expf(a - mx) + __expf(b - mx));
}

// ---------------- CSR build ------------------------------------------------
__global__ __launch_bounds__(256) void k_hist(
    const int* __restrict__ vidx, int* __restrict__ cnt)
{
    int i = blockIdx.x * 256 + threadIdx.x;
    if (i < F_N * K_N) atomicAdd(&cnt[vidx[i]], 1);
}

__global__ __launch_bounds__(256) void k_bsum(
    const int* __restrict__ cnt, int* __restrict__ bsum)
{
    __shared__ int s[256];
    int v = blockIdx.x * 256 + threadIdx.x;
    s[threadIdx.x] = (v < V_N) ? cnt[v] : 0;
    __syncthreads();
    #pragma unroll
    for (int off = 128; off >= 1; off >>= 1) {
        if (threadIdx.x < off) s[threadIdx.x] += s[threadIdx.x + off];
        __syncthreads();
    }
    if (threadIdx.x == 0) bsum[blockIdx.x] = s[0];
}

__global__ __launch_bounds__(256) void k_off(
    const int* __restrict__ cnt, const int* __restrict__ bsum,
    int* __restrict__ offsets)
{
    __shared__ int s[256];
    __shared__ int pre;
    int b = blockIdx.x, t = threadIdx.x;
    // sum of bsum[0..b-1]
    int acc = 0;
    for (int i = t; i < b; i += 256) acc += bsum[i];
    s[t] = acc; __syncthreads();
    #pragma unroll
    for (int off = 128; off >= 1; off >>= 1) {
        if (t < off) s[t] += s[t + off];
        __syncthreads();
    }
    if (t == 0) pre = s[0];
    __syncthreads();
    int base = pre;
    // exclusive scan of this block's 256 counts
    int v = b * 256 + t;
    int c = (v < V_N) ? cnt[v] : 0;
    s[t] = c; __syncthreads();
    #pragma unroll
    for (int off = 1; off < 256; off <<= 1) {
        int add = (t >= off) ? s[t - off] : 0;
        __syncthreads();
        s[t] += add;
        __syncthreads();
    }
    if (v < V_N) offsets[v] = base + s[t] - c;
}

__global__ __launch_bounds__(256) void k_fill(
    const int* __restrict__ vidx, const int* __restrict__ offsets,
    int* __restrict__ fillc, int* __restrict__ entries)
{
    int i = blockIdx.x * 256 + threadIdx.x;
    if (i >= F_N * K_N) return;
    int v = vidx[i];
    int f = i / K_N;
    int k = i - f * K_N;
    int pos = atomicAdd(&fillc[v], 1);
    entries[offsets[v] + pos] = (2 * k) * F_N + f;   // index of m-component 0
}

// ---------------- K0: m_1 from (prv_fb, prv_v2f) — no atomics ---------------
__global__ __launch_bounds__(256) void k_init(
    const float* __restrict__ prv_fb,   // [F][32]
    const float* __restrict__ prv_v2f,  // [F][5][2]
    float*       __restrict__ m_out)    // SoA [10][F]
{
    int f = blockIdx.x * 256 + threadIdx.x;
    if (f >= F_N) return;

    float fb[S_N];
    const float4* p4 = reinterpret_cast<const float4*>(prv_fb + (size_t)f * S_N);
    #pragma unroll
    for (int i = 0; i < S_N / 4; ++i) {
        float4 v = p4[i];
        fb[i*4+0] = v.x; fb[i*4+1] = v.y; fb[i*4+2] = v.z; fb[i*4+3] = v.w;
    }
    float M = fb[0];
    #pragma unroll
    for (int s = 1; s < S_N; ++s) M = fmaxf(M, fb[s]);
    float T = 0.0f;
    float S0[K_N] = {0.f, 0.f, 0.f, 0.f, 0.f};
    #pragma unroll
    for (int s = 0; s < S_N; ++s) {
        float t = __expf(fb[s] - M);
        T += t;
        #pragma unroll
        for (int k = 0; k < K_N; ++k)
            if (((s >> k) & 1) == 0) S0[k] += t;
    }
    #pragma unroll
    for (int k = 0; k < K_N; ++k) {
        float v0 = prv_v2f[(size_t)f * (K_N*2) + k*2 + 0];
        float v1 = prv_v2f[(size_t)f * (K_N*2) + k*2 + 1];
        float u0 = __logf(S0[k])     - v0;
        float u1 = __logf(T - S0[k]) - v1;
        float l  = lse2(u0, u1);
        m_out[(k*2+0)*F_N + f] = u0 - l;
        m_out[(k*2+1)*F_N + f] = u1 - l;
    }
}

// ---------------- per-iteration gather: vb_i = segsum(m_i); var_term_i ------
__global__ __launch_bounds__(256) void k_gather(
    const float* __restrict__ m,        // SoA [10][F]
    const int*   __restrict__ cnt,      // [V] (= deg)
    const int*   __restrict__ offsets,  // [V]
    const int*   __restrict__ entries,  // [F*K]
    float*       __restrict__ vb,       // [V][2] raw (unnormalized)
    float*       __restrict__ x,        // [330]
    int iter)
{
    int v = blockIdx.x * 256 + threadIdx.x;
    int lane = threadIdx.x & 63;
    float c0 = 0.0f, c1 = 0.0f;
    if (v < V_N) {
        int off = offsets[v], n = cnt[v];
        float a0 = 0.0f, a1 = 0.0f;
        for (int i = 0; i < n; ++i) {
            int j = entries[off + i];
            a0 += m[j];
            a1 += m[j + F_N];
        }
        vb[2*v+0] = a0;
        vb[2*v+1] = a1;
        float l = lse2(a0, a1);
        float vb0 = a0 - l, vb1 = a1 - l;
        float dm1 = (float)n - 1.0f;
        c0 = dm1 * __expf(vb0) * vb0;
        c1 = dm1 * __expf(vb1) * vb1;
    }
    #pragma unroll
    for (int mk = 32; mk >= 1; mk >>= 1) {
        c0 += __shfl_xor(c0, mk);
        c1 += __shfl_xor(c1, mk);
    }
    if (lane == 0) {
        atomicAdd(&x[iter*66 + 64], c0);
        atomicAdd(&x[iter*66 + 65], c1);
    }
}

// ---------------- fused factor iteration (no vb atomics) --------------------
template <bool LAST>
__global__ __launch_bounds__(256) void k_iter(
    const float* __restrict__ pot,      // [F][32]
    const int*   __restrict__ vidx,     // [F][5]
    float*       __restrict__ m,        // SoA [10][F], updated in place
    const float* __restrict__ vb,       // [V][2] raw
    float*       __restrict__ x,        // [330]
    int iter)
{
    const int lane = threadIdx.x & 63;
    __shared__ float red[256];

    int f = blockIdx.x * 256 + threadIdx.x;
    bool valid = f < F_N;
    int fc = valid ? f : (F_N - 1);

    float mm[K_N][2];
    #pragma unroll
    for (int k = 0; k < K_N; ++k) {
        mm[k][0] = m[(k*2+0)*F_N + fc];
        mm[k][1] = m[(k*2+1)*F_N + fc];
    }
    int vi[K_N];
    #pragma unroll
    for (int k = 0; k < K_N; ++k) vi[k] = vidx[(size_t)fc * K_N + k];

    float v2f[K_N][2];
    #pragma unroll
    for (int k = 0; k < K_N; ++k) {
        float a0 = vb[vi[k]*2+0] - mm[k][0];
        float a1 = vb[vi[k]*2+1] - mm[k][1];
        float l = lse2(a0, a1);
        v2f[k][0] = a0 - l;
        v2f[k][1] = a1 - l;
    }

    float potr[S_N];
    const float4* p4 = reinterpret_cast<const float4*>(pot + (size_t)fc * S_N);
    #pragma unroll
    for (int i = 0; i < S_N / 4; ++i) {
        float4 v = p4[i];
        potr[i*4+0] = v.x; potr[i*4+1] = v.y; potr[i*4+2] = v.z; potr[i*4+3] = v.w;
    }

    float fb[S_N];
    #pragma unroll
    for (int s = 0; s < S_N; ++s) {
        float w = v2f[0][s & 1] + v2f[1][(s >> 1) & 1] + v2f[2][(s >> 2) & 1]
                + v2f[3][(s >> 3) & 1] + v2f[4][(s >> 4) & 1];
        fb[s] = potr[s] + w;
    }
    float M = fb[0];
    #pragma unroll
    for (int s = 1; s < S_N; ++s) M = fmaxf(M, fb[s]);

    float T = 0.0f;
    float S0[K_N] = {0.f, 0.f, 0.f, 0.f, 0.f};
    #pragma unroll
    for (int s = 0; s < S_N; ++s) {
        float t = __expf(fb[s] - M);
        T += t;
        #pragma unroll
        for (int k = 0; k < K_N; ++k)
            if (((s >> k) & 1) == 0) S0[k] += t;
    }

    if (!LAST) {
        #pragma unroll
        for (int k = 0; k < K_N; ++k) {
            float u0 = __logf(S0[k])     - v2f[k][0];
            float u1 = __logf(T - S0[k]) - v2f[k][1];
            float l  = lse2(u0, u1);
            if (valid) {
                m[(k*2+0)*F_N + f] = u0 - l;
                m[(k*2+1)*F_N + f] = u1 - l;
            }
        }
    }

    // ---- pooled features: energy[32] | fac_ent[32] ----
    float invT = 1.0f / T;
    float logT = __logf(T);
    float arr[2 * S_N];
    #pragma unroll
    for (int s = 0; s < S_N; ++s) {
        float p   = __expf(fb[s] - M) * invT;   // exp(fb_norm)
        float fbn = fb[s] - M - logT;           // normalized fb
        arr[s]       = valid ? p * potr[s] : 0.0f;
        arr[S_N + s] = valid ? -p * fbn    : 0.0f;
    }

    // recursive-halving reduce: 64 values over 64 lanes -> lane L holds sum of value L
    #pragma unroll
    for (int mk = 32; mk >= 1; mk >>= 1) {
        bool upper = (lane & mk) != 0;
        #pragma unroll
        for (int j = 0; j < mk; ++j) {
            float send = upper ? arr[j] : arr[j + mk];
            float recv = __shfl_xor(send, mk);
            float keep = upper ? arr[j + mk] : arr[j];
            arr[j] = keep + recv;
        }
    }

    red[threadIdx.x] = arr[0];
    __syncthreads();
    if (threadIdx.x < 64) {
        float s = red[threadIdx.x] + red[64 + threadIdx.x]
                + red[128 + threadIdx.x] + red[192 + threadIdx.x];
        atomicAdd(&x[iter*66 + threadIdx.x], s);
    }
}

// ---------------- MLP -------------------------------------------------------
__global__ __launch_bounds__(64) void k_mlp1(
    const float* __restrict__ x, const float* __restrict__ w1,
    const float* __restrict__ b1, float* __restrict__ h)
{
    int j = blockIdx.x;
    int lane = threadIdx.x;
    float s = 0.0f;
    for (int i = lane; i < MLP_N; i += 64) s += x[i] * w1[(size_t)j * MLP_N + i];
    #pragma unroll
    for (int mk = 32; mk >= 1; mk >>= 1) s += __shfl_xor(s, mk);
    if (lane == 0) h[j] = fmaxf(s + b1[j], SHIFTV);
}

__global__ __launch_bounds__(64) void k_mlp2(
    const float* __restrict__ h, const float* __restrict__ w2,
    const float* __restrict__ b2, float* __restrict__ out)
{
    int lane = threadIdx.x;
    float s = 0.0f;
    for (int i = lane; i < MLP_N; i += 64) s += h[i] * w2[i];
    #pragma unroll
    for (int mk = 32; mk >= 1; mk >>= 1) s += __shfl_xor(s, mk);
    if (lane == 0) out[0] = fmaxf(s + b2[0], SHIFTV);
}

// ---------------- launch -----------------------------------------------------
extern "C" void kernel_launch(void* const* d_in, const int* in_sizes, int n_in,
                              void* d_out, int out_size, void* d_ws, size_t ws_size,
                              hipStream_t stream)
{
    (void)in_sizes; (void)n_in; (void)out_size; (void)ws_size;
    const float* pot  = (const float*)d_in[0];
    const int*   vidx = (const int*)  d_in[1];
    const float* pv2f = (const float*)d_in[2];
    // d_in[3] = prv_f2v (unused by the reference)
    const float* pfb  = (const float*)d_in[4];
    const float* w1   = (const float*)d_in[5];
    const float* b1   = (const float*)d_in[6];
    const float* w2   = (const float*)d_in[7];
    const float* b2   = (const float*)d_in[8];

    // workspace layout (4-byte units)
    float* ws      = (float*)d_ws;
    float* m       = ws;                        // 10*F            (1.5M)
    float* vb      = m + 10 * F_N;              // 2*V             (200k)
    int*   entries = (int*)(vb + 2 * V_N);      // F*K             (750k)
    int*   offsets = entries + F_N * K_N;       // V
    int*   bsum    = offsets + V_N;             // VBLK (<=512)
    int*   cnt     = bsum + 512;                // V   } zeroed
    int*   fillc   = cnt + V_N;                 // V   } zeroed
    float* x       = (float*)(fillc + V_N);     // 330 } zeroed
    float* h       = x + MLP_N;                 // 330

    // zero cnt + fillc + x (contiguous)
    size_t zbytes = (size_t)(2 * V_N + MLP_N) * sizeof(float);
    hipMemsetAsync(cnt, 0, zbytes, stream);

    // CSR build
    k_hist<<<EBLK, 256, 0, stream>>>(vidx, cnt);
    k_bsum<<<VBLK, 256, 0, stream>>>(cnt, bsum);
    k_off <<<VBLK, 256, 0, stream>>>(cnt, bsum, offsets);
    k_fill<<<EBLK, 256, 0, stream>>>(vidx, offsets, fillc, entries);

    // m_1
    k_init<<<FBLK, 256, 0, stream>>>(pfb, pv2f, m);

    for (int it = 0; it < NITER; ++it) {
        k_gather<<<VBLK, 256, 0, stream>>>(m, cnt, offsets, entries, vb, x, it);
        if (it < NITER - 1)
            k_iter<false><<<FBLK, 256, 0, stream>>>(pot, vidx, m, vb, x, it);
        else
            k_iter<true><<<FBLK, 256, 0, stream>>>(pot, vidx, m, vb, x, it);
    }

    k_mlp1<<<MLP_N, 64, 0, stream>>>(x, w1, b1, h);
    k_mlp2<<<1, 64, 0, stream>>>(h, w2, b2, (float*)d_out);
}